// Round 7
// baseline (377.716 us; speedup 1.0000x reference)
//
#include <hip/hip_runtime.h>

#define EDIM 1024
#define MROWS 16384
#define DHEAD 64
#define LSEQ 512
#define NT 16          // K tiles of 64

typedef unsigned short u16;
typedef unsigned int u32;
typedef __bf16 bf16x8 __attribute__((ext_vector_type(8)));
typedef unsigned short u16x8 __attribute__((ext_vector_type(8)));
typedef float f32x4 __attribute__((ext_vector_type(4)));

__device__ __forceinline__ u16 f2bf(float x) {
    return __builtin_bit_cast(u16, (__bf16)x);          // RTNE via HW cvt
}
__device__ __forceinline__ float bf2f(u16 h) {
    return __builtin_bit_cast(float, (u32)h << 16);
}
__device__ __forceinline__ bf16x8 ld8(const u16* p) {
    return __builtin_bit_cast(bf16x8, *(const u16x8*)p);
}
// swizzled tile read: linear [R][64] u16, byte = row*128 + (2*koff ^ ((row&7)<<4))
__device__ __forceinline__ bf16x8 ld8s(const u16* base, int row, int koff) {
    return ld8((const u16*)((const char*)base + row * 128 + ((koff * 2) ^ ((row & 7) << 4))));
}
// V^T tile read: byte = c*128 + (2*koff ^ (((c>>2)&7)<<4))
__device__ __forceinline__ bf16x8 ld8v(const u16* base, int c, int koff) {
    return ld8((const u16*)((const char*)base + c * 128 + ((koff * 2) ^ (((c >> 2) & 7) << 4))));
}
__device__ __forceinline__ void glds16(const u16* g, u16* l) {
    __builtin_amdgcn_global_load_lds(
        (const __attribute__((address_space(1))) u32*)g,
        (__attribute__((address_space(3))) u32*)l, 16, 0, 0);
}
#define MFMA(a, b, c) __builtin_amdgcn_mfma_f32_16x16x32_bf16((a), (b), (c), 0, 0, 0)
#define U4C(v, i) ((i) == 0 ? (v).x : (i) == 1 ? (v).y : (i) == 2 ? (v).z : (v).w)
#define VMCNT(n) asm volatile("s_waitcnt vmcnt(" #n ")" ::: "memory")
#define SBAR()   __builtin_amdgcn_s_barrier()

// ---------------------------------------------------------------------------
// Kernel 1: transpose + bf16 of the 4 weight matrices: WT[n][k] = bf16(W[k][n])
// ---------------------------------------------------------------------------
__global__ __launch_bounds__(256) void prep_wt_kernel(
    const float* __restrict__ Wq, const float* __restrict__ Wk,
    const float* __restrict__ Wv, const float* __restrict__ Wo,
    u16* __restrict__ WTh)
{
    const int z = blockIdx.z;
    const float* W = (z == 0) ? Wq : (z == 1) ? Wk : (z == 2) ? Wv : Wo;
    u16* th = WTh + (size_t)z * EDIM * EDIM;
    const int k0 = blockIdx.x * 64, n0 = blockIdx.y * 64;
    __shared__ float tile[64][65];
    for (int i = threadIdx.x; i < 4096; i += 256) {
        int r = i >> 6, c = i & 63;
        tile[r][c] = W[(size_t)(k0 + r) * EDIM + n0 + c];
    }
    __syncthreads();
    for (int i = threadIdx.x; i < 4096; i += 256) {
        int r = i >> 6, c = i & 63;
        th[(size_t)(n0 + r) * EDIM + k0 + c] = f2bf(tile[c][r]);
    }
}

// ---------------------------------------------------------------------------
// Kernel 2: fp32 -> bf16 convert of the three input matrices (z selects)
// ---------------------------------------------------------------------------
__global__ __launch_bounds__(256) void convert_kernel(
    const float* __restrict__ Aq, const float* __restrict__ Ak, const float* __restrict__ Av,
    u16* __restrict__ Dq, u16* __restrict__ Dk, u16* __restrict__ Dv)
{
    const int z = blockIdx.z;
    const float* src = (z == 0) ? Aq : (z == 1) ? Ak : Av;
    u16* dst = (z == 0) ? Dq : (z == 1) ? Dk : Dv;
    const size_t total8 = (size_t)MROWS * EDIM / 8;
    for (size_t i = (size_t)blockIdx.x * 256 + threadIdx.x; i < total8;
         i += (size_t)gridDim.x * 256) {
        const float4 a = *(const float4*)&src[i * 8];
        const float4 b = *(const float4*)&src[i * 8 + 4];
        ushort4 h0, h1;
        h0.x = f2bf(a.x); h0.y = f2bf(a.y); h0.z = f2bf(a.z); h0.w = f2bf(a.w);
        h1.x = f2bf(b.x); h1.y = f2bf(b.y); h1.z = f2bf(b.z); h1.w = f2bf(b.w);
        *(ushort4*)&dst[i * 8]     = h0;
        *(ushort4*)&dst[i * 8 + 4] = h1;
    }
}

// ---------------------------------------------------------------------------
// Kernel 3: 256x256x64 GEMM, 8 waves, counted-vmcnt 4-phase schedule (T3+T4),
// glds16 staging for both operands (T2 swizzle), setprio (T5), raw s_barrier.
// C[M][N] = A_bf16[M][K] @ B  (B as bf16 BT[n][k]).
// EPI 0: C -> bf16 (+bias).  EPI 1: C -> fp32 (acc + 2*bias)*sigmoid(mask)
// ---------------------------------------------------------------------------
template<int EPI>
__global__ __launch_bounds__(512, 1) void gemm256(
    const u16* __restrict__ A, const u16* __restrict__ BT,
    const float* __restrict__ bias,
    u16* __restrict__ Ch, float* __restrict__ Cf, const float* __restrict__ smask)
{
    extern __shared__ u16 lds[];           // 128 KiB: A[2][16384], B[2][16384]
    const int tid = threadIdx.x;
    const int lane = tid & 63, w = tid >> 6;
    const int wm = w >> 2, wn = w & 3;
    const int lr = lane & 15, lg = lane >> 4;
    // XCD-chunked swizzle over 256 wgs
    int D = blockIdx.x;
    int T = (D & 7) * 32 + (D >> 3);
    const int m0 = (T >> 2) * 256, n0 = (T & 3) * 256;

    u16* As0 = lds;
    u16* As1 = lds + 16384;
    u16* Bs0 = lds + 32768;
    u16* Bs1 = lds + 49152;

    auto stageB = [&](int bf, int t) {
        u16* dst = bf ? Bs1 : Bs0;
        #pragma unroll
        for (int c = 0; c < 4; ++c) {
            int idx = tid + c * 512;
            int row = idx >> 3, ch = idx & 7, sch = ch ^ (row & 7);
            glds16(&BT[(size_t)(n0 + row) * EDIM + t * 64 + sch * 8], dst + idx * 8);
        }
    };
    auto stageA = [&](int bf, int t) {
        u16* dst = bf ? As1 : As0;
        #pragma unroll
        for (int c = 0; c < 4; ++c) {
            int idx = tid + c * 512;
            int row = idx >> 3, ch = idx & 7, sch = ch ^ (row & 7);
            glds16(&A[(size_t)(m0 + row) * EDIM + t * 64 + sch * 8], dst + idx * 8);
        }
    };

    f32x4 acc[8][4] = {};
    bf16x8 bf0[4], bf1[4];

    // prologue: stage tile 0 fully, drain, pre-read B ks0
    stageB(0, 0);
    stageA(0, 0);
    VMCNT(0);
    SBAR();
    #pragma unroll
    for (int n = 0; n < 4; ++n)
        bf0[n] = ld8s(Bs0, wn * 64 + n * 16 + lr, lg * 8);

    for (int t = 0; t < NT; ++t) {
        const int cur = t & 1;
        u16* Asc = cur ? As1 : As0;
        u16* Bsc = cur ? Bs1 : Bs0;
        u16* Bsn = cur ? Bs0 : Bs1;
        const bool more = (t + 1 < NT);
        // ---- q0: MFMA m0-3 ks0 ----
        bf16x8 af[4];
        #pragma unroll
        for (int mm = 0; mm < 4; ++mm)
            af[mm] = ld8s(Asc, wm * 128 + mm * 16 + lr, lg * 8);
        if (more) { stageB(cur ^ 1, t + 1); stageA(cur ^ 1, t + 1); }  // B first, then A
        SBAR();
        __builtin_amdgcn_s_setprio(1);
        #pragma unroll
        for (int n = 0; n < 4; ++n)
            #pragma unroll
            for (int mm = 0; mm < 4; ++mm)
                acc[mm][n] = MFMA(af[mm], bf0[n], acc[mm][n]);
        __builtin_amdgcn_s_setprio(0);
        SBAR();
        // ---- q1: MFMA m4-7 ks0 ----
        bf16x8 ag[4];
        #pragma unroll
        for (int mm = 0; mm < 4; ++mm)
            ag[mm] = ld8s(Asc, wm * 128 + 64 + mm * 16 + lr, lg * 8);
        SBAR();
        __builtin_amdgcn_s_setprio(1);
        #pragma unroll
        for (int n = 0; n < 4; ++n)
            #pragma unroll
            for (int mm = 0; mm < 4; ++mm)
                acc[4 + mm][n] = MFMA(ag[mm], bf0[n], acc[4 + mm][n]);
        __builtin_amdgcn_s_setprio(0);
        SBAR();
        // ---- q2: MFMA m0-3 ks1 ----
        #pragma unroll
        for (int mm = 0; mm < 4; ++mm)
            af[mm] = ld8s(Asc, wm * 128 + mm * 16 + lr, 32 + lg * 8);
        #pragma unroll
        for (int n = 0; n < 4; ++n)
            bf1[n] = ld8s(Bsc, wn * 64 + n * 16 + lr, 32 + lg * 8);
        SBAR();
        __builtin_amdgcn_s_setprio(1);
        #pragma unroll
        for (int n = 0; n < 4; ++n)
            #pragma unroll
            for (int mm = 0; mm < 4; ++mm)
                acc[mm][n] = MFMA(af[mm], bf1[n], acc[mm][n]);
        __builtin_amdgcn_s_setprio(0);
        VMCNT(4);                         // B(t+1) landed (its 4 chunks oldest)
        SBAR();
        // ---- q3: MFMA m4-7 ks1; pre-read B[nxt] ks0 ----
        #pragma unroll
        for (int mm = 0; mm < 4; ++mm)
            ag[mm] = ld8s(Asc, wm * 128 + 64 + mm * 16 + lr, 32 + lg * 8);
        if (more) {
            #pragma unroll
            for (int n = 0; n < 4; ++n)
                bf0[n] = ld8s(Bsn, wn * 64 + n * 16 + lr, lg * 8);
        }
        SBAR();
        __builtin_amdgcn_s_setprio(1);
        #pragma unroll
        for (int n = 0; n < 4; ++n)
            #pragma unroll
            for (int mm = 0; mm < 4; ++mm)
                acc[4 + mm][n] = MFMA(ag[mm], bf1[n], acc[4 + mm][n]);
        __builtin_amdgcn_s_setprio(0);
        VMCNT(0);                         // A(t+1) landed (3-phase cover)
        SBAR();
    }
    // epilogue
    #pragma unroll
    for (int m = 0; m < 8; ++m)
        #pragma unroll
        for (int n = 0; n < 4; ++n) {
            int col = n0 + wn * 64 + n * 16 + lr;
            float bc = bias[col];
            #pragma unroll
            for (int r = 0; r < 4; ++r) {
                int row = m0 + wm * 128 + m * 16 + lg * 4 + r;
                float x = acc[m][n][r];
                if (EPI == 1) {
                    float g = 1.0f / (1.0f + __expf(-smask[row & (LSEQ - 1)]));
                    Cf[(size_t)row * EDIM + col] = (x + 2.0f * bc) * g;
                } else {
                    Ch[(size_t)row * EDIM + col] = f2bf(x + bc);
                }
            }
        }
}

// ---------------------------------------------------------------------------
// Kernel 4: ALL attention in one pass over 512 keys (unchanged from R5).
// ---------------------------------------------------------------------------
__global__ __launch_bounds__(256, 2) void attn_kernel(
    const u16* __restrict__ Q, const u16* __restrict__ K,
    const u16* __restrict__ V, u16* __restrict__ ctx)
{
    const int tid = threadIdx.x, lane = tid & 63, w = tid >> 6;
    const int lr = lane & 15, lg = lane >> 4;
    int D = (blockIdx.z * gridDim.y + blockIdx.y) * gridDim.x + blockIdx.x; // 4096
    int T = (D & 7) * 512 + (D >> 3);
    const int qq = T & 7, hd = (T >> 3) & 15, b = T >> 7;
    const int wrow = b * LSEQ + qq * 64 + w * 16;
    const int ecol = hd * DHEAD;
    const int kvbase = b * LSEQ;
    const int wt0 = qq & ~1;               // window tiles wt0, wt0+1

    __shared__ u16 Ks[2][64 * 64];
    __shared__ u16 Vt[64 * 64];
    __shared__ u16 Ps[4][3 * 16 * 72];     // per-wave strips: [lvl][q 16][72]

    u16* psw = &Ps[w][0];

    bf16x8 qf0 = ld8(&Q[(size_t)(wrow + lr) * EDIM + ecol + lg * 8]);
    bf16x8 qf1 = ld8(&Q[(size_t)(wrow + lr) * EDIM + ecol + 32 + lg * 8]);

    f32x4 o0[4] = {}, o1[4] = {}, o2[4] = {}, ow[4] = {};
    float l0 = 0, l1 = 0, l2 = 0, lw = 0;
    ushort4 vr[2][2];

    auto issueK = [&](int t, int bf) {
        #pragma unroll
        for (int c = 0; c < 2; ++c) {
            int idx = tid + c * 256;
            int row = idx >> 3, ch = idx & 7;
            int sch = ch ^ (row & 7);
            glds16(&K[(size_t)(kvbase + t * 64 + row) * EDIM + ecol + sch * 8],
                   &Ks[bf][(w * 64 + c * 256) * 8]);
        }
    };
    auto loadV = [&](int t) {
        #pragma unroll
        for (int j = 0; j < 2; ++j) {
            int i4 = tid + j * 256;
            int pr = i4 >> 4, c4 = (i4 & 15) << 2;
            vr[j][0] = *(const ushort4*)&V[(size_t)(kvbase + t * 64 + 2 * pr) * EDIM + ecol + c4];
            vr[j][1] = *(const ushort4*)&V[(size_t)(kvbase + t * 64 + 2 * pr + 1) * EDIM + ecol + c4];
        }
    };
    auto writeV = [&]() {
        #pragma unroll
        for (int j = 0; j < 2; ++j) {
            int i4 = tid + j * 256;
            int pr = i4 >> 4, c4 = (i4 & 15) << 2;
            #pragma unroll
            for (int i = 0; i < 4; ++i) {
                int c = c4 + i;
                int byo = c * 128 + ((4 * pr) ^ (((c >> 2) & 7) << 4));
                *(u32*)((char*)Vt + byo) =
                    (u32)U4C(vr[j][0], i) | ((u32)U4C(vr[j][1], i) << 16);
            }
        }
    };

    int buf = 0;
    issueK(0, 0);
    loadV(0);
    for (int t = 0; t < 8; ++t) {
        __syncthreads();                    // drains glds K(t); Vt free
        writeV();
        __syncthreads();                    // K(t), Vt(t) visible
        if (t < 7) { issueK(t + 1, buf ^ 1); loadV(t + 1); }
        const bool win = (t == wt0) | (t == wt0 + 1);

        float l0t = 0;
        #pragma unroll
        for (int nb = 0; nb < 4; ++nb) {
            bf16x8 kf0 = ld8s(&Ks[buf][0], nb * 16 + lr, lg * 8);
            bf16x8 kf1 = ld8s(&Ks[buf][0], nb * 16 + lr, 32 + lg * 8);
            f32x4 s = {};
            s = MFMA(kf0, qf0, s);          // S^T: rows=keys, cols=q (in-lane q=lr)
            s = MFMA(kf1, qf1, s);
            s *= 0.125f;
            float p00 = __expf(s[0]), p01 = __expf(s[1]);
            float p02 = __expf(s[2]), p03 = __expf(s[3]);
            float s1a = 0.5f * (s[0] + s[1]), s1b = 0.5f * (s[2] + s[3]);
            float p1a = 0.5f * __expf(s1a), p1b = 0.5f * __expf(s1b);
            float p2v = 0.25f * __expf(0.5f * (s1a + s1b));
            l0t += (p00 + p01) + (p02 + p03);
            l1 += 2.0f * (p1a + p1b);
            l2 += 4.0f * p2v;
            int rb = lr * 144 + nb * 32 + lg * 8;
            *(u32*)((char*)psw + rb)     = (u32)f2bf(p00) | ((u32)f2bf(p01) << 16);
            *(u32*)((char*)psw + rb + 4) = (u32)f2bf(p02) | ((u32)f2bf(p03) << 16);
            u32 w1a = (u32)f2bf(p1a); w1a |= w1a << 16;
            u32 w1b = (u32)f2bf(p1b); w1b |= w1b << 16;
            *(u32*)((char*)psw + 2304 + rb)     = w1a;
            *(u32*)((char*)psw + 2304 + rb + 4) = w1b;
            u32 w2 = (u32)f2bf(p2v); w2 |= w2 << 16;
            *(u32*)((char*)psw + 4608 + rb)     = w2;
            *(u32*)((char*)psw + 4608 + rb + 4) = w2;
        }
        l0 += l0t;
        if (win) lw += l0t;

        bf16x8 pa00 = ld8((const u16*)((char*)psw + lr * 144 + lg * 16));
        bf16x8 pa01 = ld8((const u16*)((char*)psw + lr * 144 + 64 + lg * 16));
        bf16x8 pa10 = ld8((const u16*)((char*)psw + 2304 + lr * 144 + lg * 16));
        bf16x8 pa11 = ld8((const u16*)((char*)psw + 2304 + lr * 144 + 64 + lg * 16));
        bf16x8 pa20 = ld8((const u16*)((char*)psw + 4608 + lr * 144 + lg * 16));
        bf16x8 pa21 = ld8((const u16*)((char*)psw + 4608 + lr * 144 + 64 + lg * 16));
        #pragma unroll
        for (int nd = 0; nd < 4; ++nd) {
            bf16x8 vb0 = ld8v(Vt, nd * 16 + lr, lg * 8);
            bf16x8 vb1 = ld8v(Vt, nd * 16 + lr, 32 + lg * 8);
            o0[nd] = MFMA(pa00, vb0, o0[nd]); o0[nd] = MFMA(pa01, vb1, o0[nd]);
            o1[nd] = MFMA(pa10, vb0, o1[nd]); o1[nd] = MFMA(pa11, vb1, o1[nd]);
            o2[nd] = MFMA(pa20, vb0, o2[nd]); o2[nd] = MFMA(pa21, vb1, o2[nd]);
            if (win) {
                ow[nd] = MFMA(pa00, vb0, ow[nd]);
                ow[nd] = MFMA(pa01, vb1, ow[nd]);
            }
        }
        buf ^= 1;
    }
    // epilogue: finish l-sums over the 4 lg groups, normalize, combine, store
    l0 += __shfl_xor(l0, 16, 64); l0 += __shfl_xor(l0, 32, 64);
    l1 += __shfl_xor(l1, 16, 64); l1 += __shfl_xor(l1, 32, 64);
    l2 += __shfl_xor(l2, 16, 64); l2 += __shfl_xor(l2, 32, 64);
    lw += __shfl_xor(lw, 16, 64); lw += __shfl_xor(lw, 32, 64);
    float c0 = (1.0f / 3.0f) / l0, c1 = (1.0f / 3.0f) / l1;
    float c2 = (1.0f / 3.0f) / l2, cw = 1.0f / lw;
    #pragma unroll
    for (int r = 0; r < 4; ++r) {
        int src = lg * 4 + r;               // q-row of D-reg r lives on lane src
        float d0 = __shfl(c0, src, 64);
        float d1 = __shfl(c1, src, 64);
        float d2 = __shfl(c2, src, 64);
        float dw = __shfl(cw, src, 64);
        #pragma unroll
        for (int nd = 0; nd < 4; ++nd) {
            float v = o0[nd][r] * d0 + o1[nd][r] * d1 + o2[nd][r] * d2 + ow[nd][r] * dw;
            ctx[(size_t)(wrow + lg * 4 + r) * EDIM + ecol + nd * 16 + lr] = f2bf(v);
        }
    }
}

// ---------------------------------------------------------------------------
extern "C" void kernel_launch(void* const* d_in, const int* in_sizes, int n_in,
                              void* d_out, int out_size, void* d_ws, size_t ws_size,
                              hipStream_t stream)
{
    const float* query = (const float*)d_in[0];
    const float* key   = (const float*)d_in[1];
    const float* value = (const float*)d_in[2];
    const float* Wq = (const float*)d_in[3];
    const float* bq = (const float*)d_in[4];
    const float* Wk = (const float*)d_in[5];
    const float* bk = (const float*)d_in[6];
    const float* Wv = (const float*)d_in[7];
    const float* bv = (const float*)d_in[8];
    const float* Wo = (const float*)d_in[9];
    const float* bo = (const float*)d_in[10];
    const float* smask = (const float*)d_in[11];

    const size_t szWT = (size_t)4 * EDIM * EDIM * 2;   // 8 MiB
    const size_t szP  = (size_t)MROWS * EDIM * 2;      // 32 MiB (bf16 plane)
    const size_t need = szWT + 7 * szP;                // 232 MiB
    if (ws_size < need) {
        hipMemsetAsync(d_out, 0x7F, (size_t)out_size * 4, stream);  // sentinel
        return;
    }
    size_t off = 0;
    auto take = [&](size_t n) -> void* {
        void* p = (char*)d_ws + off;
        off += (n + 255) & ~(size_t)255;
        return p;
    };
    u16* WTh = (u16*)take(szWT);
    u16* Aq  = (u16*)take(szP);     // bf16 inputs
    u16* Ak  = (u16*)take(szP);
    u16* Av  = (u16*)take(szP);
    u16* Qh  = (u16*)take(szP);     // projected
    u16* Kh  = (u16*)take(szP);
    u16* Vh  = (u16*)take(szP);
    u16* ctx = (u16*)take(szP);

    hipFuncSetAttribute(reinterpret_cast<const void*>(gemm256<0>),
                        hipFuncAttributeMaxDynamicSharedMemorySize, 131072);
    hipFuncSetAttribute(reinterpret_cast<const void*>(gemm256<1>),
                        hipFuncAttributeMaxDynamicSharedMemorySize, 131072);

    prep_wt_kernel<<<dim3(16, 16, 4), 256, 0, stream>>>(Wq, Wk, Wv, Wo, WTh);
    convert_kernel<<<dim3(4096, 1, 3), 256, 0, stream>>>(query, key, value, Aq, Ak, Av);

    gemm256<0><<<256, 512, 131072, stream>>>(
        Aq, WTh + 0 * (size_t)EDIM * EDIM, bq, Qh, nullptr, nullptr);
    gemm256<0><<<256, 512, 131072, stream>>>(
        Ak, WTh + 1 * (size_t)EDIM * EDIM, bk, Kh, nullptr, nullptr);
    gemm256<0><<<256, 512, 131072, stream>>>(
        Av, WTh + 2 * (size_t)EDIM * EDIM, bv, Vh, nullptr, nullptr);

    attn_kernel<<<dim3(8, 16, 32), 256, 0, stream>>>(Qh, Kh, Vh, ctx);

    gemm256<1><<<256, 512, 131072, stream>>>(
        ctx, WTh + 3 * (size_t)EDIM * EDIM, bo, nullptr, (float*)d_out, smask);
}